// Round 13
// baseline (90.507 us; speedup 1.0000x reference)
//
#include <hip/hip_runtime.h>
#include <math.h>

typedef _Float16 h2 __attribute__((ext_vector_type(2)));
typedef __fp16 hh4 __attribute__((ext_vector_type(4)));
typedef float f4 __attribute__((ext_vector_type(4)));

#define Bsz 16
#define Ssz 1024
#define TOKENS (Bsz * Ssz)   // 16384
#define Dd 64
#define Hh 8
#define QTTS 520             // qtt LDS row stride (words)

#if __has_builtin(__builtin_amdgcn_exp2f)
  #define EXPFN(x) __builtin_amdgcn_exp2f(x)
  #define SQRT_PRESCALE 0.7141921f     // sqrt((1/sqrt(8)) * log2(e))
#else
  #define EXPFN(x) __expf(x)
  #define SQRT_PRESCALE 0.5946036f     // sqrt(1/sqrt(8))
#endif

#if __has_builtin(__builtin_amdgcn_mfma_f32_16x16x16_f16)
  #define MFMA16(a, b, c) __builtin_amdgcn_mfma_f32_16x16x16_f16(a, b, c, 0, 0, 0)
#else
  #define MFMA16(a, b, c) __builtin_amdgcn_mfma_f32_16x16x16f16(a, b, c, 0, 0, 0)
#endif

__device__ __forceinline__ h2 pkrtz(float a, float b) {
#if __has_builtin(__builtin_amdgcn_cvt_pkrtz)
  return __builtin_bit_cast(h2, __builtin_amdgcn_cvt_pkrtz(a, b));
#else
  h2 r; r.x = (_Float16)a; r.y = (_Float16)b; return r;
#endif
}
__device__ __forceinline__ unsigned int as_u32(h2 v) {
  return __builtin_bit_cast(unsigned int, v);
}
__device__ __forceinline__ hh4 bc4(uint2 u) {
  return __builtin_bit_cast(hh4, u);
}

// cosine products from an 8-vector of (x + theta)
__device__ __forceinline__ void qheads_v(const float* xa, const float* th, float* o) {
  float c0 = __cosf(xa[0] + th[0]), c1 = __cosf(xa[1] + th[1]);
  float c2 = __cosf(xa[2] + th[2]), c3 = __cosf(xa[3] + th[3]);
  float c4 = __cosf(xa[4] + th[4]), c5 = __cosf(xa[5] + th[5]);
  float c6 = __cosf(xa[6] + th[6]), c7 = __cosf(xa[7] + th[7]);
  float cp = c0;
  cp *= c1; o[1] = cp; cp *= c2; o[2] = cp; cp *= c3; o[3] = cp;
  cp *= c4; o[4] = cp; cp *= c5; o[5] = cp; cp *= c6; o[6] = cp;
  cp *= c7; o[7] = cp;
  o[0] = c1 * c2 * c3 * c4 * c5 * c6 * c7;
}

// ------------------------------------------------- MFMA flash attention
// EMBED=1: layer 0 — build x rows from tokens+emb+posenc inline; split==0
// blocks also write the x slice for the tail's residual read.
// qtt row 8 = ones -> PV MFMA D-row 8 yields the softmax denominator free.
template <int EMBED>
__global__ __launch_bounds__(256, 4) void attn_kernel(
    const float* __restrict__ x, float* __restrict__ xw,
    const int* __restrict__ tokens, const float* __restrict__ emb,
    const float* __restrict__ theta,
    float* __restrict__ o_out, float* __restrict__ ps_out) {
  __shared__ unsigned int qrs[Ssz * 4 + 2];  // [k][4]: f16x2 pairs, x sqrt(scale); +2 zero pad
  __shared__ unsigned int qtt[9 * QTTS];     // [d<8 | ones][pairs (k,k+1)]
  int blk = blockIdx.x;
  int bh = blk >> 3, split = blk & 7;
  int b = bh >> 3, h = bh & 7;
  int t = threadIdx.x;

  float th[8];
#pragma unroll
  for (int i = 0; i < 8; i++) th[i] = theta[i];

  float frq[4];
  if (EMBED) {
#pragma unroll
    for (int j = 0; j < 4; j++)
      frq[j] = __expf((float)(2 * (h * 4 + j)) * (-0.14391156831f));
  }

  const float* xb = x + (size_t)b * Ssz * Dd + h * 8;

#pragma unroll
  for (int i = 0; i < 4; i++) {
    int k0 = t * 4 + i;
    float xa[8];
    if (EMBED) {
      int tok = tokens[b * Ssz + k0];
      float4 e0 = *(const float4*)&emb[(size_t)tok * Dd + h * 8];
      float4 e1 = *(const float4*)&emb[(size_t)tok * Dd + h * 8 + 4];
      float sn, cs;
      __sincosf((float)k0 * frq[0], &sn, &cs); xa[0] = e0.x + sn; xa[1] = e0.y + cs;
      __sincosf((float)k0 * frq[1], &sn, &cs); xa[2] = e0.z + sn; xa[3] = e0.w + cs;
      __sincosf((float)k0 * frq[2], &sn, &cs); xa[4] = e1.x + sn; xa[5] = e1.y + cs;
      __sincosf((float)k0 * frq[3], &sn, &cs); xa[6] = e1.z + sn; xa[7] = e1.w + cs;
      if (split == 0) {
        float4 w0, w1;
        w0.x = xa[0]; w0.y = xa[1]; w0.z = xa[2]; w0.w = xa[3];
        w1.x = xa[4]; w1.y = xa[5]; w1.z = xa[6]; w1.w = xa[7];
        *(float4*)&xw[((size_t)b * Ssz + k0) * Dd + h * 8] = w0;
        *(float4*)&xw[((size_t)b * Ssz + k0) * Dd + h * 8 + 4] = w1;
      }
    } else {
      float4 v0 = *(const float4*)(xb + (size_t)k0 * Dd);
      float4 v1 = *(const float4*)(xb + (size_t)k0 * Dd + 4);
      xa[0] = v0.x; xa[1] = v0.y; xa[2] = v0.z; xa[3] = v0.w;
      xa[4] = v1.x; xa[5] = v1.y; xa[6] = v1.z; xa[7] = v1.w;
    }
    float oa[8];
    qheads_v(xa, th, oa);
    uint4 wa;
    wa.x = as_u32(pkrtz(oa[0] * SQRT_PRESCALE, oa[1] * SQRT_PRESCALE));
    wa.y = as_u32(pkrtz(oa[2] * SQRT_PRESCALE, oa[3] * SQRT_PRESCALE));
    wa.z = as_u32(pkrtz(oa[4] * SQRT_PRESCALE, oa[5] * SQRT_PRESCALE));
    wa.w = as_u32(pkrtz(oa[6] * SQRT_PRESCALE, oa[7] * SQRT_PRESCALE));
    *(uint4*)&qrs[k0 * 4] = wa;
    // qtt: pack (k0, k0+1) pairs — stage odd rows via LDS-free trick:
    // write element halves separately using u16 stores is awkward; instead
    // keep the pairwise pack by staging two rows at a time below.
    if (i & 1) {
      // nothing: handled in pair store
    }
#pragma unroll
    for (int d = 0; d < 8; d++) {
      // store one f16 half per row into the packed pair word
      // (k0>>1) selects the pair, k0&1 the half. Use u16 write.
      unsigned short hv = (unsigned short)(as_u32(pkrtz(oa[d], oa[d])) & 0xFFFFu);
      ((unsigned short*)&qtt[d * QTTS + (k0 >> 1)])[k0 & 1] = hv;
    }
  }
  for (int j = 8 * QTTS + t; j < 9 * QTTS; j += 256) qtt[j] = 0x3C003C00u;  // ones row
  if (t == 0) { qrs[Ssz * 4] = 0; qrs[Ssz * 4 + 1] = 0; }
  __syncthreads();

  int l = t & 63, w = t >> 6;
  int g = l >> 4, rr = l & 15;
  int rt0 = split * 8 + w * 2;
  int rowA = rt0 * 16 + rr;
  int rowB = rowA + 16;
  uint2 z2; z2.x = 0; z2.y = 0;
  uint2 buA = (g < 2) ? *(const uint2*)&qrs[rowA * 4 + 2 * g] : z2;
  uint2 buB = (g < 2) ? *(const uint2*)&qrs[rowB * 4 + 2 * g] : z2;
  hh4 BrA = bc4(buA), BrB = bc4(buB);
  int aoff  = (g < 2) ? (rr * 4 + 2 * g) : (Ssz * 4);
  int astep = (g < 2) ? 64 : 0;
  int qrow  = (rr >= 8) ? 8 : rr;
  int qoff  = qrow * QTTS + 2 * g;
  f4 zf = {0.f, 0.f, 0.f, 0.f};
  f4 accA0 = zf, accB0 = zf, accA1 = zf, accB1 = zf;

#pragma unroll 4
  for (int kt = 0; kt < 64; kt += 2) {
    // hoisted LDS reads: one wait covers all four
    uint2 au0 = *(const uint2*)&qrs[aoff + kt * astep];
    uint2 au1 = *(const uint2*)&qrs[aoff + (kt + 1) * astep];
    uint2 qt0 = *(const uint2*)&qtt[qoff + kt * 8];
    uint2 qt1 = *(const uint2*)&qtt[qoff + (kt + 1) * 8];
    {
      hh4 Ak = bc4(au0);
      f4 sA = MFMA16(Ak, BrA, zf);
      f4 sB = MFMA16(Ak, BrB, zf);
      float pA0 = EXPFN(sA.x), pA1 = EXPFN(sA.y), pA2 = EXPFN(sA.z), pA3 = EXPFN(sA.w);
      float pB0 = EXPFN(sB.x), pB1 = EXPFN(sB.y), pB2 = EXPFN(sB.z), pB3 = EXPFN(sB.w);
      uint2 pbA, pbB;
      pbA.x = as_u32(pkrtz(pA0, pA1)); pbA.y = as_u32(pkrtz(pA2, pA3));
      pbB.x = as_u32(pkrtz(pB0, pB1)); pbB.y = as_u32(pkrtz(pB2, pB3));
      hh4 Aq = bc4(qt0);
      accA0 = MFMA16(Aq, bc4(pbA), accA0);
      accB0 = MFMA16(Aq, bc4(pbB), accB0);
    }
    {
      hh4 Ak = bc4(au1);
      f4 sA = MFMA16(Ak, BrA, zf);
      f4 sB = MFMA16(Ak, BrB, zf);
      float pA0 = EXPFN(sA.x), pA1 = EXPFN(sA.y), pA2 = EXPFN(sA.z), pA3 = EXPFN(sA.w);
      float pB0 = EXPFN(sB.x), pB1 = EXPFN(sB.y), pB2 = EXPFN(sB.z), pB3 = EXPFN(sB.w);
      uint2 pbA, pbB;
      pbA.x = as_u32(pkrtz(pA0, pA1)); pbA.y = as_u32(pkrtz(pA2, pA3));
      pbB.x = as_u32(pkrtz(pB0, pB1)); pbB.y = as_u32(pkrtz(pB2, pB3));
      hh4 Aq = bc4(qt1);
      accA1 = MFMA16(Aq, bc4(pbA), accA1);
      accB1 = MFMA16(Aq, bc4(pbB), accB1);
    }
  }
  f4 accA = accA0 + accA1;
  f4 accB = accB0 + accB1;

  size_t tokA = (size_t)b * Ssz + rowA;
  size_t tokB = (size_t)b * Ssz + rowB;
  if (g < 2) {                     // D rows 0-7: O^T
    *(f4*)&o_out[tokA * 64 + h * 8 + 4 * g] = accA;
    *(f4*)&o_out[tokB * 64 + h * 8 + 4 * g] = accB;
  } else if (g == 2) {             // D row 8 (reg .x): softmax denominator
    ps_out[tokA * 8 + h] = accA.x;
    ps_out[tokB * 8 + h] = accB.x;
  }
}

// ---- fused tail (MFMA): combine+LN1 -> xbuf (LDS) -> FFN+LN2, pooling.
__global__ __launch_bounds__(64) void tail_kernel(
    float* __restrict__ x, const float* __restrict__ o_out,
    const float* __restrict__ ps_out, const float* __restrict__ Wc,
    const float* __restrict__ g1, const float* __restrict__ bb1,
    const float* __restrict__ g2, const float* __restrict__ bb2,
    const float* __restrict__ fth,
    const float* __restrict__ W1, const float* __restrict__ fb1,
    const float* __restrict__ W2, const float* __restrict__ fb2,
    float* __restrict__ partial, int do_partial) {
  __shared__ float xbuf[16][68];
  int l = threadIdx.x & 63;
  int g = l >> 4, c = l & 15;
  int tok0 = blockIdx.x * 16;
  f4 zf = {0.f, 0.f, 0.f, 0.f};

  {
    hh4 Bf[4][4];
#pragma unroll
    for (int dc = 0; dc < 4; dc++)
#pragma unroll
      for (int kc = 0; kc < 4; kc++) {
        float4 wv = *(const float4*)&Wc[(size_t)(dc * 16 + c) * 64 + kc * 16 + 4 * g];
        uint2 u; u.x = as_u32(pkrtz(wv.x, wv.y)); u.y = as_u32(pkrtz(wv.z, wv.w));
        Bf[kc][dc] = bc4(u);
      }
    int tka = tok0 + c;
    hh4 Af[4];
#pragma unroll
    for (int kc = 0; kc < 4; kc++) {
      float4 o4 = *(const float4*)&o_out[(size_t)tka * 64 + kc * 16 + 4 * g];
      float inv = 1.0f / ps_out[(size_t)tka * 8 + kc * 2 + (g >> 1)];
      uint2 u;
      u.x = as_u32(pkrtz(o4.x * inv, o4.y * inv));
      u.y = as_u32(pkrtz(o4.z * inv, o4.w * inv));
      Af[kc] = bc4(u);
    }
    float yy[4][4];
#pragma unroll
    for (int dc = 0; dc < 4; dc++) {
      f4 acc = zf;
#pragma unroll
      for (int kc = 0; kc < 4; kc++) acc = MFMA16(Af[kc], Bf[kc][dc], acc);
      yy[dc][0] = acc.x; yy[dc][1] = acc.y; yy[dc][2] = acc.z; yy[dc][3] = acc.w;
    }
    float g1v[4], b1v[4];
#pragma unroll
    for (int dc = 0; dc < 4; dc++) { g1v[dc] = g1[dc * 16 + c]; b1v[dc] = bb1[dc * 16 + c]; }
#pragma unroll
    for (int r = 0; r < 4; r++) {
      int tok = tok0 + 4 * g + r;
      float rv0 = x[(size_t)tok * 64 + c]      + yy[0][r];
      float rv1 = x[(size_t)tok * 64 + 16 + c] + yy[1][r];
      float rv2 = x[(size_t)tok * 64 + 32 + c] + yy[2][r];
      float rv3 = x[(size_t)tok * 64 + 48 + c] + yy[3][r];
      float s = (rv0 + rv1) + (rv2 + rv3);
      s += __shfl_xor(s, 1, 64); s += __shfl_xor(s, 2, 64);
      s += __shfl_xor(s, 4, 64); s += __shfl_xor(s, 8, 64);
      float mu = s * (1.f / 64.f);
      float t0 = rv0 - mu, t1 = rv1 - mu, t2 = rv2 - mu, t3 = rv3 - mu;
      float q = (t0 * t0 + t1 * t1) + (t2 * t2 + t3 * t3);
      q += __shfl_xor(q, 1, 64); q += __shfl_xor(q, 2, 64);
      q += __shfl_xor(q, 4, 64); q += __shfl_xor(q, 8, 64);
      float inv = rsqrtf(q * (1.f / 64.f) + 1e-5f);
      int tk = 4 * g + r;
      xbuf[tk][c]      = t0 * inv * g1v[0] + b1v[0];
      xbuf[tk][16 + c] = t1 * inv * g1v[1] + b1v[1];
      xbuf[tk][32 + c] = t2 * inv * g1v[2] + b1v[2];
      xbuf[tk][48 + c] = t3 * inv * g1v[3] + b1v[3];
    }
  }

  float4 x4[4];
#pragma unroll
  for (int dc = 0; dc < 4; dc++)
    x4[dc] = *(const float4*)&xbuf[c][dc * 16 + 4 * g];

  uint2 uz; uz.x = 0; uz.y = 0;
  if (g < 2) {
    float4 thv = *(const float4*)&fth[4 * g];
    float z0 = __cosf(x4[0].x) * __cosf(thv.x);
    float z1 = __cosf(x4[0].y) * __cosf(thv.y);
    float z2 = __cosf(x4[0].z) * __cosf(thv.z);
    float z3 = __cosf(x4[0].w) * __cosf(thv.w);
    uz.x = as_u32(pkrtz(z0, z1)); uz.y = as_u32(pkrtz(z2, z3));
  }
  hh4 Bz = bc4(uz);

  hh4 Bh[8];
#pragma unroll
  for (int jc = 0; jc < 8; jc++) {
    uint2 uw; uw.x = 0; uw.y = 0;
    if (g < 2) {
      float4 wv = *(const float4*)&W1[(size_t)(jc * 16 + c) * 8 + 4 * g];
      uw.x = as_u32(pkrtz(wv.x, wv.y)); uw.y = as_u32(pkrtz(wv.z, wv.w));
    }
    f4 d1 = MFMA16(bc4(uw), Bz, zf);
    float4 b1v = *(const float4*)&fb1[jc * 16 + 4 * g];
    float h0 = fmaxf(d1.x + b1v.x, 0.f);
    float h1 = fmaxf(d1.y + b1v.y, 0.f);
    float h2 = fmaxf(d1.z + b1v.z, 0.f);
    float h3 = fmaxf(d1.w + b1v.w, 0.f);
    uint2 uh;
    uh.x = as_u32(pkrtz(h0, h1)); uh.y = as_u32(pkrtz(h2, h3));
    Bh[jc] = bc4(uh);
  }

  float ff[4][4];
#pragma unroll
  for (int dc = 0; dc < 4; dc++) {
    f4 acc = zf;
#pragma unroll
    for (int kc = 0; kc < 8; kc++) {
      float4 wv = *(const float4*)&W2[(size_t)(dc * 16 + c) * 128 + kc * 16 + 4 * g];
      uint2 uw;
      uw.x = as_u32(pkrtz(wv.x, wv.y)); uw.y = as_u32(pkrtz(wv.z, wv.w));
      acc = MFMA16(bc4(uw), Bh[kc], acc);
    }
    ff[dc][0] = acc.x; ff[dc][1] = acc.y; ff[dc][2] = acc.z; ff[dc][3] = acc.w;
  }

  float r2[4][4];
  float s = 0.f;
#pragma unroll
  for (int dc = 0; dc < 4; dc++) {
    float4 b2v = *(const float4*)&fb2[dc * 16 + 4 * g];
    r2[dc][0] = x4[dc].x + ff[dc][0] + b2v.x;
    r2[dc][1] = x4[dc].y + ff[dc][1] + b2v.y;
    r2[dc][2] = x4[dc].z + ff[dc][2] + b2v.z;
    r2[dc][3] = x4[dc].w + ff[dc][3] + b2v.w;
    s += (r2[dc][0] + r2[dc][1]) + (r2[dc][2] + r2[dc][3]);
  }
  s += __shfl_xor(s, 16, 64); s += __shfl_xor(s, 32, 64);
  float mu = s * (1.f / 64.f);
  float q = 0.f;
#pragma unroll
  for (int dc = 0; dc < 4; dc++) {
#pragma unroll
    for (int r = 0; r < 4; r++) { r2[dc][r] -= mu; q += r2[dc][r] * r2[dc][r]; }
  }
  q += __shfl_xor(q, 16, 64); q += __shfl_xor(q, 32, 64);
  float inv = rsqrtf(q * (1.f / 64.f) + 1e-5f);

  float xo[4][4];
#pragma unroll
  for (int dc = 0; dc < 4; dc++) {
    float4 gv = *(const float4*)&g2[dc * 16 + 4 * g];
    float4 bv = *(const float4*)&bb2[dc * 16 + 4 * g];
    xo[dc][0] = r2[dc][0] * inv * gv.x + bv.x;
    xo[dc][1] = r2[dc][1] * inv * gv.y + bv.y;
    xo[dc][2] = r2[dc][2] * inv * gv.z + bv.z;
    xo[dc][3] = r2[dc][3] * inv * gv.w + bv.w;
    float4 o4;
    o4.x = xo[dc][0]; o4.y = xo[dc][1]; o4.z = xo[dc][2]; o4.w = xo[dc][3];
    *(float4*)&x[(size_t)(tok0 + c) * 64 + dc * 16 + 4 * g] = o4;
  }

  if (do_partial) {
#pragma unroll
    for (int dc = 0; dc < 4; dc++)
#pragma unroll
      for (int r = 0; r < 4; r++) {
        float p = xo[dc][r];
        p += __shfl_xor(p, 1, 64); p += __shfl_xor(p, 2, 64);
        p += __shfl_xor(p, 4, 64); p += __shfl_xor(p, 8, 64);
        xo[dc][r] = p;
      }
    if (c == 0) {
#pragma unroll
      for (int dc = 0; dc < 4; dc++) {
        float4 o4;
        o4.x = xo[dc][0]; o4.y = xo[dc][1]; o4.z = xo[dc][2]; o4.w = xo[dc][3];
        *(float4*)&partial[(size_t)blockIdx.x * 64 + dc * 16 + 4 * g] = o4;
      }
    }
  }
}

// ------------------------------------------------ pooled mean + MLP head
__global__ __launch_bounds__(128) void head_kernel(
    const float* __restrict__ partial,   // [1024][64]
    const float* eW1, const float* eb1, const float* eW2, const float* eb2,
    const float* eW3, const float* eb3, const float* dW1, const float* db1v,
    const float* dW2, const float* db2v, const float* dW3, const float* db3v,
    const float* cW, const float* cb, float* __restrict__ out) {
  __shared__ float bufP[64];
  __shared__ float bufA[128];
  __shared__ float bufB[128];
  int b = blockIdx.x, t = threadIdx.x;
  if (t < 64) {
    float s = 0.f;
    for (int c = 0; c < 64; ++c) s += partial[(size_t)(b * 64 + c) * 64 + t];
    bufP[t] = s * (1.f / 1024.f);
  }
  __syncthreads();
  {
    float v = eb1[t];
    for (int d = 0; d < 64; d++) v = fmaf(bufP[d], eW1[t * 64 + d], v);
    bufA[t] = fmaxf(v, 0.f);
  }
  __syncthreads();
  if (t < 64) {
    float v = eb2[t];
    for (int j = 0; j < 128; j++) v = fmaf(bufA[j], eW2[t * 128 + j], v);
    bufB[t] = fmaxf(v, 0.f);
  }
  __syncthreads();
  if (t < 32) {
    float v = eb3[t];
    for (int d = 0; d < 64; d++) v = fmaf(bufB[d], eW3[t * 64 + d], v);
    bufA[t] = v;
  }
  __syncthreads();
  if (t < 64) {
    float v = db1v[t];
    for (int k = 0; k < 32; k++) v = fmaf(bufA[k], dW1[t * 32 + k], v);
    bufB[t] = fmaxf(v, 0.f);
  }
  __syncthreads();
  {
    float v = db2v[t];
    for (int k = 0; k < 64; k++) v = fmaf(bufB[k], dW2[t * 64 + k], v);
    bufA[t] = fmaxf(v, 0.f);
  }
  __syncthreads();
  if (t < 64) {
    float v = db3v[t];
    for (int j = 0; j < 128; j++) v = fmaf(bufA[j], dW3[t * 128 + j], v);
    bufB[t] = v;
  }
  __syncthreads();
  if (t < 10) {
    float v = cb[t];
    for (int d = 0; d < 64; d++) v = fmaf(bufB[d], cW[t * 64 + d], v);
    out[b * 10 + t] = v;
  }
}

extern "C" void kernel_launch(void* const* d_in, const int* in_sizes, int n_in,
                              void* d_out, int out_size, void* d_ws, size_t ws_size,
                              hipStream_t stream) {
  const int*   tokens     = (const int*)d_in[0];
  const float* emb        = (const float*)d_in[1];
  const float* attn_theta = (const float*)d_in[2];
  const float* combine_W  = (const float*)d_in[3];
  const float* ln1_g      = (const float*)d_in[4];
  const float* ln1_b      = (const float*)d_in[5];
  const float* ln2_g      = (const float*)d_in[6];
  const float* ln2_b      = (const float*)d_in[7];
  const float* ffn_theta  = (const float*)d_in[8];
  const float* ffn_W1     = (const float*)d_in[9];
  const float* ffn_b1     = (const float*)d_in[10];
  const float* ffn_W2     = (const float*)d_in[11];
  const float* ffn_b2     = (const float*)d_in[12];
  const float* enc_W1 = (const float*)d_in[13]; const float* enc_b1 = (const float*)d_in[14];
  const float* enc_W2 = (const float*)d_in[15]; const float* enc_b2 = (const float*)d_in[16];
  const float* enc_W3 = (const float*)d_in[17]; const float* enc_b3 = (const float*)d_in[18];
  const float* dec_W1 = (const float*)d_in[19]; const float* dec_b1 = (const float*)d_in[20];
  const float* dec_W2 = (const float*)d_in[21]; const float* dec_b2 = (const float*)d_in[22];
  const float* dec_W3 = (const float*)d_in[23]; const float* dec_b3 = (const float*)d_in[24];
  const float* cls_W  = (const float*)d_in[25]; const float* cls_b  = (const float*)d_in[26];

  float* x       = (float*)d_ws;                      // 1M floats
  float* o_out   = x + (size_t)TOKENS * 64;           // 1M floats
  float* ps_out  = o_out + (size_t)TOKENS * 64;       // 128K floats
  float* partial = ps_out + (size_t)TOKENS * 8;       // 64K floats
  float* out     = (float*)d_out;

  // layer 0: attention with fused embed (writes x for the tail)
  attn_kernel<1><<<128 * 8, 256, 0, stream>>>(x, x, tokens, emb,
                                              attn_theta, o_out, ps_out);
  tail_kernel<<<TOKENS / 16, 64, 0, stream>>>(
      x, o_out, ps_out, combine_W,
      ln1_g, ln1_b, ln2_g, ln2_b,
      ffn_theta, ffn_W1, ffn_b1, ffn_W2, ffn_b2, partial, 0);
  // layer 1
  attn_kernel<0><<<128 * 8, 256, 0, stream>>>(x, x, tokens, emb,
                                              attn_theta + 8, o_out, ps_out);
  tail_kernel<<<TOKENS / 16, 64, 0, stream>>>(
      x, o_out, ps_out, combine_W + 4096,
      ln1_g + 64, ln1_b + 64, ln2_g + 64, ln2_b + 64,
      ffn_theta + 8, ffn_W1 + 1024, ffn_b1 + 128,
      ffn_W2 + 8192, ffn_b2 + 64, partial, 1);
  head_kernel<<<16, 128, 0, stream>>>(partial, enc_W1, enc_b1, enc_W2, enc_b2,
                                      enc_W3, enc_b3, dec_W1, dec_b1, dec_W2,
                                      dec_b2, dec_W3, dec_b3, cls_W, cls_b, out);
}

// Round 14
// 87.197 us; speedup vs baseline: 1.0380x; 1.0380x over previous
//
#include <hip/hip_runtime.h>
#include <math.h>

typedef _Float16 h2 __attribute__((ext_vector_type(2)));
typedef __fp16 hh4 __attribute__((ext_vector_type(4)));
typedef float f4 __attribute__((ext_vector_type(4)));

#define Bsz 16
#define Ssz 1024
#define TOKENS (Bsz * Ssz)   // 16384
#define Dd 64
#define Hh 8
#define QTTS 520             // qtt LDS row stride (words)

#if __has_builtin(__builtin_amdgcn_exp2f)
  #define EXPFN(x) __builtin_amdgcn_exp2f(x)
  #define SQRT_PRESCALE 0.7141921f     // sqrt((1/sqrt(8)) * log2(e))
#else
  #define EXPFN(x) __expf(x)
  #define SQRT_PRESCALE 0.5946036f     // sqrt(1/sqrt(8))
#endif

#if __has_builtin(__builtin_amdgcn_mfma_f32_16x16x16_f16)
  #define MFMA16(a, b, c) __builtin_amdgcn_mfma_f32_16x16x16_f16(a, b, c, 0, 0, 0)
#else
  #define MFMA16(a, b, c) __builtin_amdgcn_mfma_f32_16x16x16f16(a, b, c, 0, 0, 0)
#endif

__device__ __forceinline__ h2 pkrtz(float a, float b) {
#if __has_builtin(__builtin_amdgcn_cvt_pkrtz)
  return __builtin_bit_cast(h2, __builtin_amdgcn_cvt_pkrtz(a, b));
#else
  h2 r; r.x = (_Float16)a; r.y = (_Float16)b; return r;
#endif
}
__device__ __forceinline__ unsigned int as_u32(h2 v) {
  return __builtin_bit_cast(unsigned int, v);
}
__device__ __forceinline__ hh4 bc4(uint2 u) {
  return __builtin_bit_cast(hh4, u);
}

// cosine products from an 8-vector of (x + theta)
__device__ __forceinline__ void qheads_v(const float* xa, const float* th, float* o) {
  float c0 = __cosf(xa[0] + th[0]), c1 = __cosf(xa[1] + th[1]);
  float c2 = __cosf(xa[2] + th[2]), c3 = __cosf(xa[3] + th[3]);
  float c4 = __cosf(xa[4] + th[4]), c5 = __cosf(xa[5] + th[5]);
  float c6 = __cosf(xa[6] + th[6]), c7 = __cosf(xa[7] + th[7]);
  float cp = c0;
  cp *= c1; o[1] = cp; cp *= c2; o[2] = cp; cp *= c3; o[3] = cp;
  cp *= c4; o[4] = cp; cp *= c5; o[5] = cp; cp *= c6; o[6] = cp;
  cp *= c7; o[7] = cp;
  o[0] = c1 * c2 * c3 * c4 * c5 * c6 * c7;
}

// ------------------------------------------------- MFMA flash attention
// EMBED=1: layer 0 — build x rows from tokens+emb+posenc inline; split==0
// blocks also write the x slice for the tail's residual read.
// qtt row 8 = ones -> PV MFMA D-row 8 yields the softmax denominator free.
template <int EMBED>
__global__ __launch_bounds__(256, 4) void attn_kernel(
    const float* __restrict__ x, float* __restrict__ xw,
    const int* __restrict__ tokens, const float* __restrict__ emb,
    const float* __restrict__ theta,
    float* __restrict__ o_out, float* __restrict__ ps_out) {
  __shared__ unsigned int qrs[Ssz * 4 + 2];  // [k][4]: f16x2 pairs, x sqrt(scale); +2 zero pad
  __shared__ unsigned int qtt[9 * QTTS];     // [d<8 | ones][pairs (k,k+1)]
  int blk = blockIdx.x;
  int bh = blk >> 3, split = blk & 7;
  int b = bh >> 3, h = bh & 7;
  int t = threadIdx.x;

  float th[8];
#pragma unroll
  for (int i = 0; i < 8; i++) th[i] = theta[i];

  float frq[4];
  if (EMBED) {
#pragma unroll
    for (int j = 0; j < 4; j++)
      frq[j] = __expf((float)(2 * (h * 4 + j)) * (-0.14391156831f));
  }

  const float* xb = x + (size_t)b * Ssz * Dd + h * 8;

#pragma unroll
  for (int i = 0; i < 4; i += 2) {
    int k0 = t * 4 + i;
    float xa[8], xc[8];
    if (EMBED) {
      int tokA = tokens[b * Ssz + k0];
      int tokB = tokens[b * Ssz + k0 + 1];
      float4 e0 = *(const float4*)&emb[(size_t)tokA * Dd + h * 8];
      float4 e1 = *(const float4*)&emb[(size_t)tokA * Dd + h * 8 + 4];
      float4 f0 = *(const float4*)&emb[(size_t)tokB * Dd + h * 8];
      float4 f1 = *(const float4*)&emb[(size_t)tokB * Dd + h * 8 + 4];
      float sn, cs;
      __sincosf((float)k0 * frq[0], &sn, &cs); xa[0] = e0.x + sn; xa[1] = e0.y + cs;
      __sincosf((float)k0 * frq[1], &sn, &cs); xa[2] = e0.z + sn; xa[3] = e0.w + cs;
      __sincosf((float)k0 * frq[2], &sn, &cs); xa[4] = e1.x + sn; xa[5] = e1.y + cs;
      __sincosf((float)k0 * frq[3], &sn, &cs); xa[6] = e1.z + sn; xa[7] = e1.w + cs;
      __sincosf((float)(k0 + 1) * frq[0], &sn, &cs); xc[0] = f0.x + sn; xc[1] = f0.y + cs;
      __sincosf((float)(k0 + 1) * frq[1], &sn, &cs); xc[2] = f0.z + sn; xc[3] = f0.w + cs;
      __sincosf((float)(k0 + 1) * frq[2], &sn, &cs); xc[4] = f1.x + sn; xc[5] = f1.y + cs;
      __sincosf((float)(k0 + 1) * frq[3], &sn, &cs); xc[6] = f1.z + sn; xc[7] = f1.w + cs;
      if (split == 0) {
        float4 w0, w1;
        w0.x = xa[0]; w0.y = xa[1]; w0.z = xa[2]; w0.w = xa[3];
        w1.x = xa[4]; w1.y = xa[5]; w1.z = xa[6]; w1.w = xa[7];
        *(float4*)&xw[((size_t)b * Ssz + k0) * Dd + h * 8] = w0;
        *(float4*)&xw[((size_t)b * Ssz + k0) * Dd + h * 8 + 4] = w1;
        w0.x = xc[0]; w0.y = xc[1]; w0.z = xc[2]; w0.w = xc[3];
        w1.x = xc[4]; w1.y = xc[5]; w1.z = xc[6]; w1.w = xc[7];
        *(float4*)&xw[((size_t)b * Ssz + k0 + 1) * Dd + h * 8] = w0;
        *(float4*)&xw[((size_t)b * Ssz + k0 + 1) * Dd + h * 8 + 4] = w1;
      }
    } else {
      float4 v0 = *(const float4*)(xb + (size_t)k0 * Dd);
      float4 v1 = *(const float4*)(xb + (size_t)k0 * Dd + 4);
      float4 v2 = *(const float4*)(xb + (size_t)(k0 + 1) * Dd);
      float4 v3 = *(const float4*)(xb + (size_t)(k0 + 1) * Dd + 4);
      xa[0] = v0.x; xa[1] = v0.y; xa[2] = v0.z; xa[3] = v0.w;
      xa[4] = v1.x; xa[5] = v1.y; xa[6] = v1.z; xa[7] = v1.w;
      xc[0] = v2.x; xc[1] = v2.y; xc[2] = v2.z; xc[3] = v2.w;
      xc[4] = v3.x; xc[5] = v3.y; xc[6] = v3.z; xc[7] = v3.w;
    }
    float oa[8], ob[8];
    qheads_v(xa, th, oa);
    qheads_v(xc, th, ob);
    uint4 wa, wb;
    wa.x = as_u32(pkrtz(oa[0] * SQRT_PRESCALE, oa[1] * SQRT_PRESCALE));
    wa.y = as_u32(pkrtz(oa[2] * SQRT_PRESCALE, oa[3] * SQRT_PRESCALE));
    wa.z = as_u32(pkrtz(oa[4] * SQRT_PRESCALE, oa[5] * SQRT_PRESCALE));
    wa.w = as_u32(pkrtz(oa[6] * SQRT_PRESCALE, oa[7] * SQRT_PRESCALE));
    wb.x = as_u32(pkrtz(ob[0] * SQRT_PRESCALE, ob[1] * SQRT_PRESCALE));
    wb.y = as_u32(pkrtz(ob[2] * SQRT_PRESCALE, ob[3] * SQRT_PRESCALE));
    wb.z = as_u32(pkrtz(ob[4] * SQRT_PRESCALE, ob[5] * SQRT_PRESCALE));
    wb.w = as_u32(pkrtz(ob[6] * SQRT_PRESCALE, ob[7] * SQRT_PRESCALE));
    *(uint4*)&qrs[k0 * 4] = wa;
    *(uint4*)&qrs[(k0 + 1) * 4] = wb;
#pragma unroll
    for (int d = 0; d < 8; d++)
      qtt[d * QTTS + (k0 >> 1)] = as_u32(pkrtz(oa[d], ob[d]));  // unscaled pair
  }
  for (int j = 8 * QTTS + t; j < 9 * QTTS; j += 256) qtt[j] = 0x3C003C00u;  // ones row
  if (t == 0) { qrs[Ssz * 4] = 0; qrs[Ssz * 4 + 1] = 0; }
  __syncthreads();

  int l = t & 63, w = t >> 6;
  int g = l >> 4, rr = l & 15;
  int rt0 = split * 8 + w * 2;
  int rowA = rt0 * 16 + rr;
  int rowB = rowA + 16;
  uint2 z2; z2.x = 0; z2.y = 0;
  uint2 buA = (g < 2) ? *(const uint2*)&qrs[rowA * 4 + 2 * g] : z2;
  uint2 buB = (g < 2) ? *(const uint2*)&qrs[rowB * 4 + 2 * g] : z2;
  hh4 BrA = bc4(buA), BrB = bc4(buB);
  int aoff  = (g < 2) ? (rr * 4 + 2 * g) : (Ssz * 4);
  int astep = (g < 2) ? 64 : 0;
  int qrow  = (rr >= 8) ? 8 : rr;
  int qoff  = qrow * QTTS + 2 * g;
  f4 zf = {0.f, 0.f, 0.f, 0.f};
  f4 accA0 = zf, accB0 = zf, accA1 = zf, accB1 = zf;

#pragma unroll 4
  for (int kt = 0; kt < 64; kt += 2) {
    uint2 au0 = *(const uint2*)&qrs[aoff + kt * astep];
    uint2 au1 = *(const uint2*)&qrs[aoff + (kt + 1) * astep];
    uint2 qt0 = *(const uint2*)&qtt[qoff + kt * 8];
    uint2 qt1 = *(const uint2*)&qtt[qoff + (kt + 1) * 8];
    {
      hh4 Ak = bc4(au0);
      f4 sA = MFMA16(Ak, BrA, zf);
      f4 sB = MFMA16(Ak, BrB, zf);
      float pA0 = EXPFN(sA.x), pA1 = EXPFN(sA.y), pA2 = EXPFN(sA.z), pA3 = EXPFN(sA.w);
      float pB0 = EXPFN(sB.x), pB1 = EXPFN(sB.y), pB2 = EXPFN(sB.z), pB3 = EXPFN(sB.w);
      uint2 pbA, pbB;
      pbA.x = as_u32(pkrtz(pA0, pA1)); pbA.y = as_u32(pkrtz(pA2, pA3));
      pbB.x = as_u32(pkrtz(pB0, pB1)); pbB.y = as_u32(pkrtz(pB2, pB3));
      hh4 Aq = bc4(qt0);
      accA0 = MFMA16(Aq, bc4(pbA), accA0);
      accB0 = MFMA16(Aq, bc4(pbB), accB0);
    }
    {
      hh4 Ak = bc4(au1);
      f4 sA = MFMA16(Ak, BrA, zf);
      f4 sB = MFMA16(Ak, BrB, zf);
      float pA0 = EXPFN(sA.x), pA1 = EXPFN(sA.y), pA2 = EXPFN(sA.z), pA3 = EXPFN(sA.w);
      float pB0 = EXPFN(sB.x), pB1 = EXPFN(sB.y), pB2 = EXPFN(sB.z), pB3 = EXPFN(sB.w);
      uint2 pbA, pbB;
      pbA.x = as_u32(pkrtz(pA0, pA1)); pbA.y = as_u32(pkrtz(pA2, pA3));
      pbB.x = as_u32(pkrtz(pB0, pB1)); pbB.y = as_u32(pkrtz(pB2, pB3));
      hh4 Aq = bc4(qt1);
      accA1 = MFMA16(Aq, bc4(pbA), accA1);
      accB1 = MFMA16(Aq, bc4(pbB), accB1);
    }
  }
  f4 accA = accA0 + accA1;
  f4 accB = accB0 + accB1;

  size_t tokA = (size_t)b * Ssz + rowA;
  size_t tokB = (size_t)b * Ssz + rowB;
  if (g < 2) {                     // D rows 0-7: O^T
    *(f4*)&o_out[tokA * 64 + h * 8 + 4 * g] = accA;
    *(f4*)&o_out[tokB * 64 + h * 8 + 4 * g] = accB;
  } else if (g == 2) {             // D row 8 (reg .x): softmax denominator
    ps_out[tokA * 8 + h] = accA.x;
    ps_out[tokB * 8 + h] = accB.x;
  }
}

// ---- fused tail (MFMA): combine+LN1 -> xbuf (LDS) -> FFN+LN2, pooling.
__global__ __launch_bounds__(64) void tail_kernel(
    float* __restrict__ x, const float* __restrict__ o_out,
    const float* __restrict__ ps_out, const float* __restrict__ Wc,
    const float* __restrict__ g1, const float* __restrict__ bb1,
    const float* __restrict__ g2, const float* __restrict__ bb2,
    const float* __restrict__ fth,
    const float* __restrict__ W1, const float* __restrict__ fb1,
    const float* __restrict__ W2, const float* __restrict__ fb2,
    float* __restrict__ partial, int do_partial) {
  __shared__ float xbuf[16][68];
  int l = threadIdx.x & 63;
  int g = l >> 4, c = l & 15;
  int tok0 = blockIdx.x * 16;
  f4 zf = {0.f, 0.f, 0.f, 0.f};

  {
    hh4 Bf[4][4];
#pragma unroll
    for (int dc = 0; dc < 4; dc++)
#pragma unroll
      for (int kc = 0; kc < 4; kc++) {
        float4 wv = *(const float4*)&Wc[(size_t)(dc * 16 + c) * 64 + kc * 16 + 4 * g];
        uint2 u; u.x = as_u32(pkrtz(wv.x, wv.y)); u.y = as_u32(pkrtz(wv.z, wv.w));
        Bf[kc][dc] = bc4(u);
      }
    int tka = tok0 + c;
    hh4 Af[4];
#pragma unroll
    for (int kc = 0; kc < 4; kc++) {
      float4 o4 = *(const float4*)&o_out[(size_t)tka * 64 + kc * 16 + 4 * g];
      float inv = 1.0f / ps_out[(size_t)tka * 8 + kc * 2 + (g >> 1)];
      uint2 u;
      u.x = as_u32(pkrtz(o4.x * inv, o4.y * inv));
      u.y = as_u32(pkrtz(o4.z * inv, o4.w * inv));
      Af[kc] = bc4(u);
    }
    float yy[4][4];
#pragma unroll
    for (int dc = 0; dc < 4; dc++) {
      f4 acc = zf;
#pragma unroll
      for (int kc = 0; kc < 4; kc++) acc = MFMA16(Af[kc], Bf[kc][dc], acc);
      yy[dc][0] = acc.x; yy[dc][1] = acc.y; yy[dc][2] = acc.z; yy[dc][3] = acc.w;
    }
    float g1v[4], b1v[4];
#pragma unroll
    for (int dc = 0; dc < 4; dc++) { g1v[dc] = g1[dc * 16 + c]; b1v[dc] = bb1[dc * 16 + c]; }
#pragma unroll
    for (int r = 0; r < 4; r++) {
      int tok = tok0 + 4 * g + r;
      float rv0 = x[(size_t)tok * 64 + c]      + yy[0][r];
      float rv1 = x[(size_t)tok * 64 + 16 + c] + yy[1][r];
      float rv2 = x[(size_t)tok * 64 + 32 + c] + yy[2][r];
      float rv3 = x[(size_t)tok * 64 + 48 + c] + yy[3][r];
      float s = (rv0 + rv1) + (rv2 + rv3);
      s += __shfl_xor(s, 1, 64); s += __shfl_xor(s, 2, 64);
      s += __shfl_xor(s, 4, 64); s += __shfl_xor(s, 8, 64);
      float mu = s * (1.f / 64.f);
      float t0 = rv0 - mu, t1 = rv1 - mu, t2 = rv2 - mu, t3 = rv3 - mu;
      float q = (t0 * t0 + t1 * t1) + (t2 * t2 + t3 * t3);
      q += __shfl_xor(q, 1, 64); q += __shfl_xor(q, 2, 64);
      q += __shfl_xor(q, 4, 64); q += __shfl_xor(q, 8, 64);
      float inv = rsqrtf(q * (1.f / 64.f) + 1e-5f);
      int tk = 4 * g + r;
      xbuf[tk][c]      = t0 * inv * g1v[0] + b1v[0];
      xbuf[tk][16 + c] = t1 * inv * g1v[1] + b1v[1];
      xbuf[tk][32 + c] = t2 * inv * g1v[2] + b1v[2];
      xbuf[tk][48 + c] = t3 * inv * g1v[3] + b1v[3];
    }
  }

  float4 x4[4];
#pragma unroll
  for (int dc = 0; dc < 4; dc++)
    x4[dc] = *(const float4*)&xbuf[c][dc * 16 + 4 * g];

  uint2 uz; uz.x = 0; uz.y = 0;
  if (g < 2) {
    float4 thv = *(const float4*)&fth[4 * g];
    float z0 = __cosf(x4[0].x) * __cosf(thv.x);
    float z1 = __cosf(x4[0].y) * __cosf(thv.y);
    float z2 = __cosf(x4[0].z) * __cosf(thv.z);
    float z3 = __cosf(x4[0].w) * __cosf(thv.w);
    uz.x = as_u32(pkrtz(z0, z1)); uz.y = as_u32(pkrtz(z2, z3));
  }
  hh4 Bz = bc4(uz);

  hh4 Bh[8];
#pragma unroll
  for (int jc = 0; jc < 8; jc++) {
    uint2 uw; uw.x = 0; uw.y = 0;
    if (g < 2) {
      float4 wv = *(const float4*)&W1[(size_t)(jc * 16 + c) * 8 + 4 * g];
      uw.x = as_u32(pkrtz(wv.x, wv.y)); uw.y = as_u32(pkrtz(wv.z, wv.w));
    }
    f4 d1 = MFMA16(bc4(uw), Bz, zf);
    float4 b1v = *(const float4*)&fb1[jc * 16 + 4 * g];
    float h0 = fmaxf(d1.x + b1v.x, 0.f);
    float h1 = fmaxf(d1.y + b1v.y, 0.f);
    float h2 = fmaxf(d1.z + b1v.z, 0.f);
    float h3 = fmaxf(d1.w + b1v.w, 0.f);
    uint2 uh;
    uh.x = as_u32(pkrtz(h0, h1)); uh.y = as_u32(pkrtz(h2, h3));
    Bh[jc] = bc4(uh);
  }

  float ff[4][4];
#pragma unroll
  for (int dc = 0; dc < 4; dc++) {
    f4 acc = zf;
#pragma unroll
    for (int kc = 0; kc < 8; kc++) {
      float4 wv = *(const float4*)&W2[(size_t)(dc * 16 + c) * 128 + kc * 16 + 4 * g];
      uint2 uw;
      uw.x = as_u32(pkrtz(wv.x, wv.y)); uw.y = as_u32(pkrtz(wv.z, wv.w));
      acc = MFMA16(bc4(uw), Bh[kc], acc);
    }
    ff[dc][0] = acc.x; ff[dc][1] = acc.y; ff[dc][2] = acc.z; ff[dc][3] = acc.w;
  }

  float r2[4][4];
  float s = 0.f;
#pragma unroll
  for (int dc = 0; dc < 4; dc++) {
    float4 b2v = *(const float4*)&fb2[dc * 16 + 4 * g];
    r2[dc][0] = x4[dc].x + ff[dc][0] + b2v.x;
    r2[dc][1] = x4[dc].y + ff[dc][1] + b2v.y;
    r2[dc][2] = x4[dc].z + ff[dc][2] + b2v.z;
    r2[dc][3] = x4[dc].w + ff[dc][3] + b2v.w;
    s += (r2[dc][0] + r2[dc][1]) + (r2[dc][2] + r2[dc][3]);
  }
  s += __shfl_xor(s, 16, 64); s += __shfl_xor(s, 32, 64);
  float mu = s * (1.f / 64.f);
  float q = 0.f;
#pragma unroll
  for (int dc = 0; dc < 4; dc++) {
#pragma unroll
    for (int r = 0; r < 4; r++) { r2[dc][r] -= mu; q += r2[dc][r] * r2[dc][r]; }
  }
  q += __shfl_xor(q, 16, 64); q += __shfl_xor(q, 32, 64);
  float inv = rsqrtf(q * (1.f / 64.f) + 1e-5f);

  float xo[4][4];
#pragma unroll
  for (int dc = 0; dc < 4; dc++) {
    float4 gv = *(const float4*)&g2[dc * 16 + 4 * g];
    float4 bv = *(const float4*)&bb2[dc * 16 + 4 * g];
    xo[dc][0] = r2[dc][0] * inv * gv.x + bv.x;
    xo[dc][1] = r2[dc][1] * inv * gv.y + bv.y;
    xo[dc][2] = r2[dc][2] * inv * gv.z + bv.z;
    xo[dc][3] = r2[dc][3] * inv * gv.w + bv.w;
    float4 o4;
    o4.x = xo[dc][0]; o4.y = xo[dc][1]; o4.z = xo[dc][2]; o4.w = xo[dc][3];
    *(float4*)&x[(size_t)(tok0 + c) * 64 + dc * 16 + 4 * g] = o4;
  }

  if (do_partial) {
#pragma unroll
    for (int dc = 0; dc < 4; dc++)
#pragma unroll
      for (int r = 0; r < 4; r++) {
        float p = xo[dc][r];
        p += __shfl_xor(p, 1, 64); p += __shfl_xor(p, 2, 64);
        p += __shfl_xor(p, 4, 64); p += __shfl_xor(p, 8, 64);
        xo[dc][r] = p;
      }
    if (c == 0) {
#pragma unroll
      for (int dc = 0; dc < 4; dc++) {
        float4 o4;
        o4.x = xo[dc][0]; o4.y = xo[dc][1]; o4.z = xo[dc][2]; o4.w = xo[dc][3];
        *(float4*)&partial[(size_t)blockIdx.x * 64 + dc * 16 + 4 * g] = o4;
      }
    }
  }
}

// ------------------------------------------------ pooled mean + MLP head
__global__ __launch_bounds__(128) void head_kernel(
    const float* __restrict__ partial,   // [1024][64]
    const float* eW1, const float* eb1, const float* eW2, const float* eb2,
    const float* eW3, const float* eb3, const float* dW1, const float* db1v,
    const float* dW2, const float* db2v, const float* dW3, const float* db3v,
    const float* cW, const float* cb, float* __restrict__ out) {
  __shared__ float bufP[64];
  __shared__ float bufA[128];
  __shared__ float bufB[128];
  int b = blockIdx.x, t = threadIdx.x;
  if (t < 64) {
    float s = 0.f;
    for (int c = 0; c < 64; ++c) s += partial[(size_t)(b * 64 + c) * 64 + t];
    bufP[t] = s * (1.f / 1024.f);
  }
  __syncthreads();
  {
    float v = eb1[t];
    for (int d = 0; d < 64; d++) v = fmaf(bufP[d], eW1[t * 64 + d], v);
    bufA[t] = fmaxf(v, 0.f);
  }
  __syncthreads();
  if (t < 64) {
    float v = eb2[t];
    for (int j = 0; j < 128; j++) v = fmaf(bufA[j], eW2[t * 128 + j], v);
    bufB[t] = fmaxf(v, 0.f);
  }
  __syncthreads();
  if (t < 32) {
    float v = eb3[t];
    for (int d = 0; d < 64; d++) v = fmaf(bufB[d], eW3[t * 64 + d], v);
    bufA[t] = v;
  }
  __syncthreads();
  if (t < 64) {
    float v = db1v[t];
    for (int k = 0; k < 32; k++) v = fmaf(bufA[k], dW1[t * 32 + k], v);
    bufB[t] = fmaxf(v, 0.f);
  }
  __syncthreads();
  {
    float v = db2v[t];
    for (int k = 0; k < 64; k++) v = fmaf(bufB[k], dW2[t * 64 + k], v);
    bufA[t] = fmaxf(v, 0.f);
  }
  __syncthreads();
  if (t < 64) {
    float v = db3v[t];
    for (int j = 0; j < 128; j++) v = fmaf(bufA[j], dW3[t * 128 + j], v);
    bufB[t] = v;
  }
  __syncthreads();
  if (t < 10) {
    float v = cb[t];
    for (int d = 0; d < 64; d++) v = fmaf(bufB[d], cW[t * 64 + d], v);
    out[b * 10 + t] = v;
  }
}

extern "C" void kernel_launch(void* const* d_in, const int* in_sizes, int n_in,
                              void* d_out, int out_size, void* d_ws, size_t ws_size,
                              hipStream_t stream) {
  const int*   tokens     = (const int*)d_in[0];
  const float* emb        = (const float*)d_in[1];
  const float* attn_theta = (const float*)d_in[2];
  const float* combine_W  = (const float*)d_in[3];
  const float* ln1_g      = (const float*)d_in[4];
  const float* ln1_b      = (const float*)d_in[5];
  const float* ln2_g      = (const float*)d_in[6];
  const float* ln2_b      = (const float*)d_in[7];
  const float* ffn_theta  = (const float*)d_in[8];
  const float* ffn_W1     = (const float*)d_in[9];
  const float* ffn_b1     = (const float*)d_in[10];
  const float* ffn_W2     = (const float*)d_in[11];
  const float* ffn_b2     = (const float*)d_in[12];
  const float* enc_W1 = (const float*)d_in[13]; const float* enc_b1 = (const float*)d_in[14];
  const float* enc_W2 = (const float*)d_in[15]; const float* enc_b2 = (const float*)d_in[16];
  const float* enc_W3 = (const float*)d_in[17]; const float* enc_b3 = (const float*)d_in[18];
  const float* dec_W1 = (const float*)d_in[19]; const float* dec_b1 = (const float*)d_in[20];
  const float* dec_W2 = (const float*)d_in[21]; const float* dec_b2 = (const float*)d_in[22];
  const float* dec_W3 = (const float*)d_in[23]; const float* dec_b3 = (const float*)d_in[24];
  const float* cls_W  = (const float*)d_in[25]; const float* cls_b  = (const float*)d_in[26];

  float* x       = (float*)d_ws;                      // 1M floats
  float* o_out   = x + (size_t)TOKENS * 64;           // 1M floats
  float* ps_out  = o_out + (size_t)TOKENS * 64;       // 128K floats
  float* partial = ps_out + (size_t)TOKENS * 8;       // 64K floats
  float* out     = (float*)d_out;

  // layer 0: attention with fused embed (writes x for the tail)
  attn_kernel<1><<<128 * 8, 256, 0, stream>>>(x, x, tokens, emb,
                                              attn_theta, o_out, ps_out);
  tail_kernel<<<TOKENS / 16, 64, 0, stream>>>(
      x, o_out, ps_out, combine_W,
      ln1_g, ln1_b, ln2_g, ln2_b,
      ffn_theta, ffn_W1, ffn_b1, ffn_W2, ffn_b2, partial, 0);
  // layer 1
  attn_kernel<0><<<128 * 8, 256, 0, stream>>>(x, x, tokens, emb,
                                              attn_theta + 8, o_out, ps_out);
  tail_kernel<<<TOKENS / 16, 64, 0, stream>>>(
      x, o_out, ps_out, combine_W + 4096,
      ln1_g + 64, ln1_b + 64, ln2_g + 64, ln2_b + 64,
      ffn_theta + 8, ffn_W1 + 1024, ffn_b1 + 128,
      ffn_W2 + 8192, ffn_b2 + 64, partial, 1);
  head_kernel<<<16, 128, 0, stream>>>(partial, enc_W1, enc_b1, enc_W2, enc_b2,
                                      enc_W3, enc_b3, dec_W1, dec_b1, dec_W2,
                                      dec_b2, dec_W3, dec_b3, cls_W, cls_b, out);
}